// Round 1
// baseline (928.962 us; speedup 1.0000x reference)
//
#include <hip/hip_runtime.h>
#include <math.h>

#define B_  128
#define S_  512
#define U_  1024
#define T_  48

// ---------------------------------------------------------------------------
// Kernel 1: scores[b,s,t] = sum_u H[b,s,u] * W[u,t] + bias[t]
// One row (b,s) per thread. H read as float4 (each lane walks its own row;
// lines fully reused via L1/L2). W indices are lane-uniform -> scalar loads.
// 48 fp32 accumulators per thread.
// ---------------------------------------------------------------------------
__global__ __launch_bounds__(256) void gemm_scores(
    const float* __restrict__ H, const float* __restrict__ W,
    const float* __restrict__ bias, float* __restrict__ scores)
{
    const int row = blockIdx.x * blockDim.x + threadIdx.x;  // 0..65535
    const float4* h4 = reinterpret_cast<const float4*>(H + (size_t)row * U_);

    float acc[T_];
#pragma unroll
    for (int t = 0; t < T_; ++t) acc[t] = 0.f;

#pragma unroll 2
    for (int k4 = 0; k4 < U_ / 4; ++k4) {
        const float4 h = h4[k4];
        const float* wp = W + k4 * 4 * T_;
#pragma unroll
        for (int t = 0; t < T_; ++t) {
            float a = acc[t];
            a = fmaf(h.x, wp[t         ], a);
            a = fmaf(h.y, wp[T_   + t  ], a);
            a = fmaf(h.z, wp[2*T_ + t  ], a);
            a = fmaf(h.w, wp[3*T_ + t  ], a);
            acc[t] = a;
        }
    }

    float* out = scores + (size_t)row * T_;
#pragma unroll
    for (int t = 0; t < T_; ++t) out[t] = acc[t] + bias[t];
}

// ---------------------------------------------------------------------------
// Kernel 2: CRF forward + numerator per batch. One wave (64 threads) / batch.
// Lane t owns lp[t] (t<48). exp(transitions) column E[:,t] cached in VGPRs.
// Per step: shift by lane0's lp, exp, broadcast via LDS, 48-FMA dot, log.
// Early exit at s_len[b] (mask keeps lp unchanged past it).
// ---------------------------------------------------------------------------
__global__ __launch_bounds__(64) void crf_forward(
    const float* __restrict__ scores, const float* __restrict__ start_tr,
    const float* __restrict__ end_tr, const float* __restrict__ trans,
    const int* __restrict__ tag, const int* __restrict__ s_len,
    float* __restrict__ out)
{
    __shared__ float E[T_ * T_];
    __shared__ float Tr[T_ * T_];
    __shared__ __align__(16) float abuf[64];

    const int b = blockIdx.x;
    const int lane = threadIdx.x;

    for (int i = lane; i < T_ * T_; i += 64) {
        const float v = trans[i];
        Tr[i] = v;
        E[i]  = __expf(v);
    }
    __syncthreads();

    const int len = s_len[b];                      // in [1, S]
    const float* sc = scores + (size_t)b * S_ * T_;
    const int* tg = tag + (size_t)b * S_;

    // ---- numerator: emit-at-tag + transition pairs, parallel over s ----
    float nsum = 0.f;
    for (int s = lane; s < len; s += 64) {
        const int t = tg[s];
        nsum += sc[s * T_ + t];
        if (s >= 1) nsum += Tr[tg[s - 1] * T_ + t];
    }
#pragma unroll
    for (int off = 32; off >= 1; off >>= 1)
        nsum += __shfl_xor(nsum, off);

    // ---- cache E column for this lane in registers ----
    const int col = (lane < T_) ? lane : 0;        // clamp, lanes>=48 unused
    float e[T_];
#pragma unroll
    for (int j = 0; j < T_; ++j) e[j] = E[j * T_ + col];

    // ---- forward recursion ----
    float lp = (lane < T_) ? (start_tr[lane] + sc[lane]) : -1e30f;

    float emit_next = (len > 1) ? sc[T_ + col] : 0.f;
    for (int s = 1; s < len; ++s) {
        const float m = __shfl(lp, 0);             // loose shift (lane0 ref)
        const float p = __expf(lp - m);            // lanes>=48 -> 0
        abuf[lane] = p;
        __syncthreads();

        const float emit = emit_next;
        if (s + 1 < len) emit_next = sc[(s + 1) * T_ + col];

        float s0 = 0.f, s1 = 0.f, s2 = 0.f, s3 = 0.f;
        const float4* a4 = reinterpret_cast<const float4*>(abuf);
#pragma unroll
        for (int j4 = 0; j4 < T_ / 4; ++j4) {
            const float4 pv = a4[j4];
            s0 = fmaf(pv.x, e[4 * j4 + 0], s0);
            s1 = fmaf(pv.y, e[4 * j4 + 1], s1);
            s2 = fmaf(pv.z, e[4 * j4 + 2], s2);
            s3 = fmaf(pv.w, e[4 * j4 + 3], s3);
        }
        __syncthreads();                           // abuf reuse next iter

        const float sum = (s0 + s1) + (s2 + s3);
        const float nlp = m + __logf(sum) + emit;
        lp = (lane < T_) ? nlp : -1e30f;
    }

    // ---- log_Z = logsumexp(lp + end_tr) ----
    float z = (lane < T_) ? (lp + end_tr[lane]) : -1e30f;
    float mz = z;
#pragma unroll
    for (int off = 32; off >= 1; off >>= 1)
        mz = fmaxf(mz, __shfl_xor(mz, off));
    float ez = __expf(z - mz);
#pragma unroll
    for (int off = 32; off >= 1; off >>= 1)
        ez += __shfl_xor(ez, off);
    const float logZ = mz + __logf(ez);

    if (lane == 0) {
        const float num = nsum + start_tr[tg[0]] + end_tr[tg[len - 1]];
        out[b] = num - logZ;
    }
}

// ---------------------------------------------------------------------------
extern "C" void kernel_launch(void* const* d_in, const int* in_sizes, int n_in,
                              void* d_out, int out_size, void* d_ws, size_t ws_size,
                              hipStream_t stream) {
    const float* H        = (const float*)d_in[0];
    const float* W        = (const float*)d_in[1];
    const float* bias     = (const float*)d_in[2];
    const float* start_tr = (const float*)d_in[3];
    const float* end_tr   = (const float*)d_in[4];
    const float* trans    = (const float*)d_in[5];
    const int*   tag      = (const int*)d_in[6];
    const int*   s_len    = (const int*)d_in[7];
    // d_in[8] = w_mask, redundant with s_len (mask = s < s_len by construction)

    float* scores = (float*)d_ws;   // 65536 x 48 fp32 = 12.6 MB

    hipLaunchKernelGGL(gemm_scores, dim3((B_ * S_) / 256), dim3(256), 0, stream,
                       H, W, bias, scores);
    hipLaunchKernelGGL(crf_forward, dim3(B_), dim3(64), 0, stream,
                       scores, start_tr, end_tr, trans, tag, s_len, (float*)d_out);
}